// Round 5
// baseline (345.672 us; speedup 1.0000x reference)
//
#include <hip/hip_runtime.h>
#include <hip/hip_bf16.h>

#define NH 8
#define BB 4
#define NN 1024
#define DD 512
#define DH 64
#define JSPLIT 8

typedef __bf16 bf16x8 __attribute__((ext_vector_type(8)));
typedef float f32x4 __attribute__((ext_vector_type(4)));

__device__ __forceinline__ unsigned short f2bf(float f) {
    union { float f; unsigned u; } v; v.f = f;
    unsigned u = v.u;
    unsigned r = u + 0x7FFFu + ((u >> 16) & 1u);   // RNE
    return (unsigned short)(r >> 16);
}

// ---- k_prep: fused weight prep.
// blocks 0..511   : Wt[n][c] = bf16(W[c][n] * (n<512 ? 1/sqrt(512) : 1)) via 32x32 LDS transpose
//                   (+ bias_eff when c-block==0)
// blocks 512..639 : wv_eff[c][h] = sum_dh W[c, 2D+h*64+dh]*w_force[h*64+dh], wave per c
// block 640       : s_bias[h] = sum_dh b_proj[2D+h*64+dh]*w_force[h*64+dh]
__global__ __launch_bounds__(256) void k_prep(const float* __restrict__ W,
                                              const float* __restrict__ b_proj,
                                              const float* __restrict__ w_force,
                                              unsigned short* __restrict__ Wt,
                                              float* __restrict__ bias_eff,
                                              float* __restrict__ wv_eff,
                                              float* __restrict__ s_bias) {
    __shared__ float tile[32][33];
    int bx = blockIdx.x;
    int t = threadIdx.x;
    const float rscale = 0.044194173824159216f;   // 1/sqrt(512)
    if (bx < 512) {
        int c0 = (bx & 15) * 32;   // K dim (0..511)
        int n0 = (bx >> 4) * 32;   // N dim (0..1023)
        for (int i = 0; i < 4; ++i) {
            int idx = t + i * 256;
            int r = idx >> 5, cn = idx & 31;
            tile[r][cn] = W[(c0 + r) * (3 * DD) + n0 + cn];
        }
        __syncthreads();
        for (int i = 0; i < 4; ++i) {
            int idx = t + i * 256;
            int nn = idx >> 5, cc = idx & 31;
            float v = tile[cc][nn];
            int n = n0 + nn;
            if (n < DD) v *= rscale;
            Wt[n * DD + c0 + cc] = f2bf(v);
        }
        if ((bx & 15) == 0 && t < 32) {
            int n = n0 + t;
            bias_eff[n] = b_proj[n] * (n < DD ? rscale : 1.0f);
        }
        return;
    }
    int wave = t >> 6, lane = t & 63;
    if (bx == 640) {
        if (wave == 0) {
            for (int hh = 0; hh < NH; ++hh) {
                float p = b_proj[2 * DD + hh * DH + lane] * w_force[hh * DH + lane];
                for (int off = 32; off; off >>= 1) p += __shfl_xor(p, off);
                if (lane == 0) s_bias[hh] = p;
            }
        }
        return;
    }
    int c = (bx - 512) * 4 + wave;   // 0..511
    const float* wr = W + (size_t)c * (3 * DD) + 2 * DD;
    #pragma unroll
    for (int hh = 0; hh < NH; ++hh) {
        float p = wr[hh * DH + lane] * w_force[hh * DH + lane];
        for (int off = 32; off; off >>= 1) p += __shfl_xor(p, off);
        if (lane == 0) wv_eff[c * 8 + hh] = p;
    }
}

// ---- k_s: thread per (row,h). 256 blocks x 128 thr.
__global__ __launch_bounds__(128) void k_s(const float* __restrict__ emb,
                                           const float* __restrict__ wv_eff,
                                           const float* __restrict__ s_bias,
                                           float* __restrict__ s_ws) {
    int t = blockIdx.x * 128 + threadIdx.x;   // 0..32767
    int row = t >> 3;                          // b*1024 + j
    int h = t & 7;
    const float* er = emb + (size_t)row * DD;
    const float* wp = wv_eff + h;
    float acc = 0.f;
    #pragma unroll 8
    for (int c4 = 0; c4 < DD / 4; ++c4) {
        float4 e = *(const float4*)(er + c4 * 4);
        acc += e.x * wp[(c4 * 4 + 0) * 8];
        acc += e.y * wp[(c4 * 4 + 1) * 8];
        acc += e.z * wp[(c4 * 4 + 2) * 8];
        acc += e.w * wp[(c4 * 4 + 3) * 8];
    }
    int b = row >> 10, j = row & 1023;
    s_ws[(b * 8 + h) * NN + j] = acc + s_bias[h];
}

// ---- k_gemm: 128x128 tile, 4 waves, 4x4 accs/wave. A staged from fp32 emb with
// in-register bf16 convert (k_emb eliminated). M=4096, N=1024, K=512.
__global__ __launch_bounds__(256) void k_gemm(const float* __restrict__ emb,
                                              const unsigned short* __restrict__ Wt,
                                              const float* __restrict__ bias_eff,
                                              unsigned short* __restrict__ qb,
                                              unsigned short* __restrict__ kb) {
    __shared__ __align__(16) unsigned short a_s[128 * 32];
    __shared__ __align__(16) unsigned short b_s[128 * 32];
    int m0 = blockIdx.x * 128, n0 = blockIdx.y * 128;
    int t = threadIdx.x;
    int wave = t >> 6, lane = t & 63;
    int wr = (wave >> 1) * 64, wc = (wave & 1) * 64;
    int qd = lane >> 4, c = lane & 15;
    int sr = t >> 2, sg = (t & 3) * 8;
    f32x4 acc[4][4] = {};
    for (int k0 = 0; k0 < DD; k0 += 32) {
        float4 x0 = *(const float4*)(emb + (size_t)(m0 + sr) * DD + k0 + sg);
        float4 x1 = *(const float4*)(emb + (size_t)(m0 + sr) * DD + k0 + sg + 4);
        float4 y0 = *(const float4*)(emb + (size_t)(m0 + 64 + sr) * DD + k0 + sg);
        float4 y1 = *(const float4*)(emb + (size_t)(m0 + 64 + sr) * DD + k0 + sg + 4);
        uint4 bv0 = *(const uint4*)(Wt + (size_t)(n0 + sr) * DD + k0 + sg);
        uint4 bv1 = *(const uint4*)(Wt + (size_t)(n0 + 64 + sr) * DD + k0 + sg);
        union { unsigned short u[8]; uint4 v; } px, py;
        px.u[0] = f2bf(x0.x); px.u[1] = f2bf(x0.y); px.u[2] = f2bf(x0.z); px.u[3] = f2bf(x0.w);
        px.u[4] = f2bf(x1.x); px.u[5] = f2bf(x1.y); px.u[6] = f2bf(x1.z); px.u[7] = f2bf(x1.w);
        py.u[0] = f2bf(y0.x); py.u[1] = f2bf(y0.y); py.u[2] = f2bf(y0.z); py.u[3] = f2bf(y0.w);
        py.u[4] = f2bf(y1.x); py.u[5] = f2bf(y1.y); py.u[6] = f2bf(y1.z); py.u[7] = f2bf(y1.w);
        __syncthreads();
        *(uint4*)(&a_s[sr * 32 + sg]) = px.v;
        *(uint4*)(&a_s[(64 + sr) * 32 + sg]) = py.v;
        *(uint4*)(&b_s[sr * 32 + sg]) = bv0;
        *(uint4*)(&b_s[(64 + sr) * 32 + sg]) = bv1;
        __syncthreads();
        bf16x8 af[4], bfr[4];
        #pragma unroll
        for (int mi = 0; mi < 4; ++mi)
            af[mi] = *(const bf16x8*)(&a_s[(wr + mi * 16 + c) * 32 + qd * 8]);
        #pragma unroll
        for (int ni = 0; ni < 4; ++ni)
            bfr[ni] = *(const bf16x8*)(&b_s[(wc + ni * 16 + c) * 32 + qd * 8]);
        #pragma unroll
        for (int mi = 0; mi < 4; ++mi)
            #pragma unroll
            for (int ni = 0; ni < 4; ++ni)
                acc[mi][ni] = __builtin_amdgcn_mfma_f32_16x16x32_bf16(af[mi], bfr[ni], acc[mi][ni], 0, 0, 0);
    }
    bool isQ = (n0 < DD);
    unsigned short* dst = isQ ? qb : kb;
    int nb = isQ ? n0 : n0 - DD;
    #pragma unroll
    for (int mi = 0; mi < 4; ++mi)
        #pragma unroll
        for (int ni = 0; ni < 4; ++ni) {
            int col = nb + wc + ni * 16 + c;
            float be = bias_eff[isQ ? col : col + DD];
            #pragma unroll
            for (int r = 0; r < 4; ++r) {
                int row = m0 + wr + mi * 16 + qd * 4 + r;
                dst[(size_t)row * DD + col] = f2bf(acc[mi][ni][r] + be);
            }
        }
}

// ---- k_attn: transposed-score fused attention, register pipeline, 512 thr = 8 waves = 8 heads.
// __launch_bounds__(512,4): VGPR capped at 128 -> 4 waves/SIMD (m69: waves halve at vgpr=128).
// Grid covers (chunk[8], b[4], itile[64]) = 2048 blocks; each block does 16 i x 128 j.
__global__ __launch_bounds__(512, 4) void k_attn(const unsigned short* __restrict__ qb,
                                                 const unsigned short* __restrict__ kb,
                                                 const float* __restrict__ s_ws,
                                                 const float* __restrict__ d_mask,
                                                 const float* __restrict__ dirs,
                                                 float* __restrict__ part) {
    int blk = blockIdx.x;
    int itile = blk & 63;
    int rest = blk >> 6;             // 0..31
    int b = rest & 3;
    int chunk = rest >> 2;           // 0..7
    int i0 = itile * 16;
    int j_base = chunk * (NN / JSPLIT);
    int t = threadIdx.x;
    int h = t >> 6;
    int lane = t & 63, qd = lane >> 4, c = lane & 15;
    int i = i0 + c;

    const unsigned short* qbase = qb + ((size_t)(b * NN + i) * DD + h * DH + qd * 8);
    bf16x8 aq0 = *(const bf16x8*)(qbase);
    bf16x8 aq1 = *(const bf16x8*)(qbase + 32);

    const unsigned short* kp = kb + ((size_t)(b * NN + j_base + c) * DD + h * DH + qd * 8);
    const float* mp = d_mask + (size_t)(b * NH + h) * NN * NN + (size_t)i * NN + j_base + qd * 4;
    const float* sp = s_ws + (b * NH + h) * NN + j_base + qd * 4;
    const float* dp = dirs + (((size_t)b * NN + i) * NN + j_base + qd * 4) * 3;

    float acc0 = 0.f, acc1 = 0.f, acc2 = 0.f, l = 0.f;

    // prologue: load iteration 0
    bf16x8 ck0 = *(const bf16x8*)(kp);
    bf16x8 ck1 = *(const bf16x8*)(kp + 32);
    f32x4 cmk = __builtin_nontemporal_load((const f32x4*)mp);
    f32x4 csj = *(const f32x4*)sp;
    f32x4 cd0 = *(const f32x4*)(dp);
    f32x4 cd1 = *(const f32x4*)(dp + 4);
    f32x4 cd2 = *(const f32x4*)(dp + 8);

    auto step = [&](bf16x8 k0, bf16x8 k1, f32x4 mk, f32x4 sj, f32x4 d0, f32x4 d1, f32x4 d2) {
        f32x4 sc = {0.f, 0.f, 0.f, 0.f};
        sc = __builtin_amdgcn_mfma_f32_16x16x32_bf16(k0, aq0, sc, 0, 0, 0);
        sc = __builtin_amdgcn_mfma_f32_16x16x32_bf16(k1, aq1, sc, 0, 0, 0);
        float p0 = __expf(sc[0] + mk.x);
        float p1 = __expf(sc[1] + mk.y);
        float p2 = __expf(sc[2] + mk.z);
        float p3 = __expf(sc[3] + mk.w);
        l += p0 + p1 + p2 + p3;
        float t0 = p0 * sj.x, t1 = p1 * sj.y, t2 = p2 * sj.z, t3 = p3 * sj.w;
        // dirs layout: j=jq+0 -> d0.xyz ; jq+1 -> d0.w d1.xy ; jq+2 -> d1.zw d2.x ; jq+3 -> d2.yzw
        acc0 += t0 * d0.x + t1 * d0.w + t2 * d1.z + t3 * d2.y;
        acc1 += t0 * d0.y + t1 * d1.x + t2 * d1.w + t3 * d2.z;
        acc2 += t0 * d0.z + t1 * d1.y + t2 * d2.x + t3 * d2.w;
    };

    #pragma unroll
    for (int it = 0; it < NN / JSPLIT / 16 - 1; ++it) {
        kp += 16 * DD; mp += 16; sp += 16; dp += 48;
        bf16x8 nk0 = *(const bf16x8*)(kp);
        bf16x8 nk1 = *(const bf16x8*)(kp + 32);
        f32x4 nmk = __builtin_nontemporal_load((const f32x4*)mp);
        f32x4 nsj = *(const f32x4*)sp;
        f32x4 nd0 = *(const f32x4*)(dp);
        f32x4 nd1 = *(const f32x4*)(dp + 4);
        f32x4 nd2 = *(const f32x4*)(dp + 8);
        step(ck0, ck1, cmk, csj, cd0, cd1, cd2);
        ck0 = nk0; ck1 = nk1; cmk = nmk; csj = nsj; cd0 = nd0; cd1 = nd1; cd2 = nd2;
    }
    step(ck0, ck1, cmk, csj, cd0, cd1, cd2);   // epilogue iteration

    // reduce over qd (lanes sharing same i)
    l    += __shfl_xor(l, 16);    l    += __shfl_xor(l, 32);
    acc0 += __shfl_xor(acc0, 16); acc0 += __shfl_xor(acc0, 32);
    acc1 += __shfl_xor(acc1, 16); acc1 += __shfl_xor(acc1, 32);
    acc2 += __shfl_xor(acc2, 16); acc2 += __shfl_xor(acc2, 32);
    if (qd == 0) {
        f32x4 o; o[0] = l; o[1] = acc0; o[2] = acc1; o[3] = acc2;
        *(f32x4*)(part + ((((size_t)(chunk * BB + b)) * NH + h) * NN + i) * 4) = o;
    }
}

// ---- k_fin: out[b,i,a] = b_force + sum_h (sum_ch acc)/(sum_ch l)
__global__ __launch_bounds__(256) void k_fin(const float4* __restrict__ part,
                                             const float* __restrict__ b_force,
                                             float* __restrict__ out) {
    int t = blockIdx.x * 256 + threadIdx.x;   // 0..4095
    int b = t >> 10, i = t & 1023;
    float o0, o1, o2;
    o0 = o1 = o2 = b_force[0];
    #pragma unroll
    for (int h = 0; h < NH; ++h) {
        float lx = 0.f, a0 = 0.f, a1 = 0.f, a2 = 0.f;
        #pragma unroll
        for (int ch = 0; ch < JSPLIT; ++ch) {
            float4 p = part[(((size_t)(ch * BB + b) * NH + h) * NN) + i];
            lx += p.x; a0 += p.y; a1 += p.z; a2 += p.w;
        }
        float inv = 1.0f / lx;
        o0 += a0 * inv; o1 += a1 * inv; o2 += a2 * inv;
    }
    out[t * 3 + 0] = o0;
    out[t * 3 + 1] = o1;
    out[t * 3 + 2] = o2;
}

extern "C" void kernel_launch(void* const* d_in, const int* in_sizes, int n_in,
                              void* d_out, int out_size, void* d_ws, size_t ws_size,
                              hipStream_t stream) {
    (void)in_sizes; (void)n_in; (void)out_size; (void)ws_size;
    const float* emb     = (const float*)d_in[0];
    const float* dirs    = (const float*)d_in[1];
    const float* d_mask  = (const float*)d_in[2];
    const float* W       = (const float*)d_in[3];
    const float* b_proj  = (const float*)d_in[4];
    const float* w_force = (const float*)d_in[5];
    const float* b_force = (const float*)d_in[6];
    float* out = (float*)d_out;

    char* ws = (char*)d_ws;
    float* wv_eff   = (float*)ws;                       // 4096 f
    float* s_bias   = wv_eff + 4096;                    // 8 f
    float* bias_eff = s_bias + 8;                       // 1024 f
    float* s_ws     = bias_eff + 1024;                  // 32768 f
    unsigned short* Wt = (unsigned short*)(s_ws + 32768);    // 512K elems
    unsigned short* qb = Wt + 1024 * 512;               // 2M elems
    unsigned short* kb = qb + 4096 * 512;               // 2M elems
    float* part = (float*)(kb + 4096 * 512);            // 32*8*1024 float4 = 4 MB

    hipLaunchKernelGGL(k_prep, dim3(641),     dim3(256), 0, stream,
                       W, b_proj, w_force, Wt, bias_eff, wv_eff, s_bias);
    hipLaunchKernelGGL(k_s,    dim3(256),     dim3(128), 0, stream, emb, wv_eff, s_bias, s_ws);
    hipLaunchKernelGGL(k_gemm, dim3(32, 8),   dim3(256), 0, stream, emb, Wt, bias_eff, qb, kb);
    hipLaunchKernelGGL(k_attn, dim3(BB * 64 * JSPLIT), dim3(512), 0, stream,
                       qb, kb, s_ws, d_mask, dirs, part);
    hipLaunchKernelGGL(k_fin,  dim3(16),      dim3(256), 0, stream, (const float4*)part, b_force, out);
}

// Round 6
// 313.969 us; speedup vs baseline: 1.1010x; 1.1010x over previous
//
#include <hip/hip_runtime.h>
#include <hip/hip_bf16.h>

#define NH 8
#define BB 4
#define NN 1024
#define DD 512
#define DH 64
#define SCS 1032   // sc LDS row stride (ushorts): 1024 + 8 pad (2-way bank alias only)

typedef __bf16 bf16x8 __attribute__((ext_vector_type(8)));
typedef float f32x4 __attribute__((ext_vector_type(4)));

__device__ __forceinline__ unsigned short f2bf(float f) {
    union { float f; unsigned u; } v; v.f = f;
    unsigned u = v.u;
    unsigned r = u + 0x7FFFu + ((u >> 16) & 1u);   // RNE
    return (unsigned short)(r >> 16);
}
__device__ __forceinline__ float b2f(unsigned short u) {
    union { unsigned u; float f; } cv; cv.u = ((unsigned)u) << 16; return cv.f;
}

// ---- k_prep: fused weight prep + s precompute.
// blocks 0..511   : Wt[n][c] = bf16(W[c][n] * (n<512 ? 1/sqrt(512) : 1)) (+bias_eff when c-blk 0)
// blocks 512..639 : wv_eff[c][h] = sum_dh W[c, 2D+h*64+dh]*w_force[h*64+dh]
// block 640       : s_bias[h]
// blocks 641..768 : s_ws[b,h,j] = emb_row . wv_eff[:,h]... NOTE: needs wv_eff!  -> computed
//                   independently here from W directly would re-do work; instead s path reads
//                   emb and W-derived wv_eff is NOT ready within same kernel. So s blocks
//                   recompute the tiny dot directly: s = sum_c emb[row,c] * wvrow(c,h) requires
//                   wv_eff... To stay single-pass, s blocks compute wv on the fly per h? Too
//                   costly. Instead: s blocks compute s from emb and W via two-level loop over
//                   dh with w_force folded: s[row,h] = sum_dh (sum_c emb[c] W[c,2D+h*64+dh]) wf
//                   is O(512*64) per row — too big. => keep s in its own kernel (launch 3).
__global__ __launch_bounds__(256) void k_prep(const float* __restrict__ W,
                                              const float* __restrict__ b_proj,
                                              const float* __restrict__ w_force,
                                              unsigned short* __restrict__ Wt,
                                              float* __restrict__ bias_eff,
                                              float* __restrict__ wv_eff,
                                              float* __restrict__ s_bias) {
    __shared__ float tile[32][33];
    int bx = blockIdx.x;
    int t = threadIdx.x;
    const float rscale = 0.044194173824159216f;   // 1/sqrt(512)
    if (bx < 512) {
        int c0 = (bx & 15) * 32;   // K dim (0..511)
        int n0 = (bx >> 4) * 32;   // N dim (0..1023)
        for (int i = 0; i < 4; ++i) {
            int idx = t + i * 256;
            int r = idx >> 5, cn = idx & 31;
            tile[r][cn] = W[(c0 + r) * (3 * DD) + n0 + cn];
        }
        __syncthreads();
        for (int i = 0; i < 4; ++i) {
            int idx = t + i * 256;
            int nn = idx >> 5, cc = idx & 31;
            float v = tile[cc][nn];
            int n = n0 + nn;
            if (n < DD) v *= rscale;
            Wt[n * DD + c0 + cc] = f2bf(v);
        }
        if ((bx & 15) == 0 && t < 32) {
            int n = n0 + t;
            bias_eff[n] = b_proj[n] * (n < DD ? rscale : 1.0f);
        }
        return;
    }
    int wave = t >> 6, lane = t & 63;
    if (bx == 640) {
        if (wave == 0) {
            for (int hh = 0; hh < NH; ++hh) {
                float p = b_proj[2 * DD + hh * DH + lane] * w_force[hh * DH + lane];
                for (int off = 32; off; off >>= 1) p += __shfl_xor(p, off);
                if (lane == 0) s_bias[hh] = p;
            }
        }
        return;
    }
    int c = (bx - 512) * 4 + wave;   // 0..511
    const float* wr = W + (size_t)c * (3 * DD) + 2 * DD;
    #pragma unroll
    for (int hh = 0; hh < NH; ++hh) {
        float p = wr[hh * DH + lane] * w_force[hh * DH + lane];
        for (int off = 32; off; off >>= 1) p += __shfl_xor(p, off);
        if (lane == 0) wv_eff[c * 8 + hh] = p;
    }
}

// ---- k_s: thread per (row,h). 256 blocks x 128 thr.
__global__ __launch_bounds__(128) void k_s(const float* __restrict__ emb,
                                           const float* __restrict__ wv_eff,
                                           const float* __restrict__ s_bias,
                                           float* __restrict__ s_ws) {
    int t = blockIdx.x * 128 + threadIdx.x;   // 0..32767
    int row = t >> 3;                          // b*1024 + j
    int h = t & 7;
    const float* er = emb + (size_t)row * DD;
    const float* wp = wv_eff + h;
    float acc = 0.f;
    #pragma unroll 8
    for (int c4 = 0; c4 < DD / 4; ++c4) {
        float4 e = *(const float4*)(er + c4 * 4);
        acc += e.x * wp[(c4 * 4 + 0) * 8];
        acc += e.y * wp[(c4 * 4 + 1) * 8];
        acc += e.z * wp[(c4 * 4 + 2) * 8];
        acc += e.w * wp[(c4 * 4 + 3) * 8];
    }
    int b = row >> 10, j = row & 1023;
    s_ws[(b * 8 + h) * NN + j] = acc + s_bias[h];
}

// ---- k_gemm: 128x128 tile, 4 waves, 4x4 accs/wave. A staged from fp32 emb with
// in-register bf16 convert. M=4096, N=1024, K=512.
__global__ __launch_bounds__(256) void k_gemm(const float* __restrict__ emb,
                                              const unsigned short* __restrict__ Wt,
                                              const float* __restrict__ bias_eff,
                                              unsigned short* __restrict__ qb,
                                              unsigned short* __restrict__ kb) {
    __shared__ __align__(16) unsigned short a_s[128 * 32];
    __shared__ __align__(16) unsigned short b_s[128 * 32];
    int m0 = blockIdx.x * 128, n0 = blockIdx.y * 128;
    int t = threadIdx.x;
    int wave = t >> 6, lane = t & 63;
    int wr = (wave >> 1) * 64, wc = (wave & 1) * 64;
    int qd = lane >> 4, c = lane & 15;
    int sr = t >> 2, sg = (t & 3) * 8;
    f32x4 acc[4][4] = {};
    for (int k0 = 0; k0 < DD; k0 += 32) {
        float4 x0 = *(const float4*)(emb + (size_t)(m0 + sr) * DD + k0 + sg);
        float4 x1 = *(const float4*)(emb + (size_t)(m0 + sr) * DD + k0 + sg + 4);
        float4 y0 = *(const float4*)(emb + (size_t)(m0 + 64 + sr) * DD + k0 + sg);
        float4 y1 = *(const float4*)(emb + (size_t)(m0 + 64 + sr) * DD + k0 + sg + 4);
        uint4 bv0 = *(const uint4*)(Wt + (size_t)(n0 + sr) * DD + k0 + sg);
        uint4 bv1 = *(const uint4*)(Wt + (size_t)(n0 + 64 + sr) * DD + k0 + sg);
        union { unsigned short u[8]; uint4 v; } px, py;
        px.u[0] = f2bf(x0.x); px.u[1] = f2bf(x0.y); px.u[2] = f2bf(x0.z); px.u[3] = f2bf(x0.w);
        px.u[4] = f2bf(x1.x); px.u[5] = f2bf(x1.y); px.u[6] = f2bf(x1.z); px.u[7] = f2bf(x1.w);
        py.u[0] = f2bf(y0.x); py.u[1] = f2bf(y0.y); py.u[2] = f2bf(y0.z); py.u[3] = f2bf(y0.w);
        py.u[4] = f2bf(y1.x); py.u[5] = f2bf(y1.y); py.u[6] = f2bf(y1.z); py.u[7] = f2bf(y1.w);
        __syncthreads();
        *(uint4*)(&a_s[sr * 32 + sg]) = px.v;
        *(uint4*)(&a_s[(64 + sr) * 32 + sg]) = py.v;
        *(uint4*)(&b_s[sr * 32 + sg]) = bv0;
        *(uint4*)(&b_s[(64 + sr) * 32 + sg]) = bv1;
        __syncthreads();
        bf16x8 af[4], bfr[4];
        #pragma unroll
        for (int mi = 0; mi < 4; ++mi)
            af[mi] = *(const bf16x8*)(&a_s[(wr + mi * 16 + c) * 32 + qd * 8]);
        #pragma unroll
        for (int ni = 0; ni < 4; ++ni)
            bfr[ni] = *(const bf16x8*)(&b_s[(wc + ni * 16 + c) * 32 + qd * 8]);
        #pragma unroll
        for (int mi = 0; mi < 4; ++mi)
            #pragma unroll
            for (int ni = 0; ni < 4; ++ni)
                acc[mi][ni] = __builtin_amdgcn_mfma_f32_16x16x32_bf16(af[mi], bfr[ni], acc[mi][ni], 0, 0, 0);
    }
    bool isQ = (n0 < DD);
    unsigned short* dst = isQ ? qb : kb;
    int nb = isQ ? n0 : n0 - DD;
    #pragma unroll
    for (int mi = 0; mi < 4; ++mi)
        #pragma unroll
        for (int ni = 0; ni < 4; ++ni) {
            int col = nb + wc + ni * 16 + c;
            float be = bias_eff[isQ ? col : col + DD];
            #pragma unroll
            for (int r = 0; r < 4; ++r) {
                int row = m0 + wr + mi * 16 + qd * 4 + r;
                dst[(size_t)row * DD + col] = f2bf(acc[mi][ni][r] + be);
            }
        }
}

// ---- k_attn: two-phase. Block = (b, h, 16-i-tile), 256 thr = 4 waves.
// Phase A: sc[16][1024] = QK^T via MFMA -> LDS (bf16). Wave w owns j-slice [w*256, w*256+256).
// Phase B: pure streaming. Wave w owns i-rows w*4..w*4+3; lane owns j = seg*256 + lane*4.
//          mask/s contiguous 1KB/instr; dirs 3x dwordx4; sc from LDS. No MFMA -> 16 independent
//          (row x seg) load groups for deep MLP.
__global__ __launch_bounds__(256) void k_attn(const unsigned short* __restrict__ qb,
                                              const unsigned short* __restrict__ kb,
                                              const float* __restrict__ s_ws,
                                              const float* __restrict__ d_mask,
                                              const float* __restrict__ dirs,
                                              float* __restrict__ part) {
    __shared__ unsigned short sc_s[16 * SCS];   // 33 KB
    int blk = blockIdx.x;
    int itile = blk & 63;
    int bh = blk >> 6;          // b*NH + h
    int h = bh & 7;
    int b = bh >> 3;
    int i0 = itile * 16;
    int t = threadIdx.x;
    int w = t >> 6, lane = t & 63, qd = lane >> 4, c = lane & 15;

    // ---- phase A ----
    const unsigned short* qbase = qb + ((size_t)(b * NN + i0 + c) * DD + h * DH + qd * 8);
    bf16x8 aq0 = *(const bf16x8*)(qbase);
    bf16x8 aq1 = *(const bf16x8*)(qbase + 32);
    int j0w = w * 256;
    #pragma unroll
    for (int jt = 0; jt < 16; ++jt) {
        int j0 = j0w + jt * 16;
        const unsigned short* kba = kb + ((size_t)(b * NN + j0 + c) * DD + h * DH + qd * 8);
        bf16x8 kf0 = *(const bf16x8*)(kba);
        bf16x8 kf1 = *(const bf16x8*)(kba + 32);
        f32x4 sc = {0.f, 0.f, 0.f, 0.f};
        sc = __builtin_amdgcn_mfma_f32_16x16x32_bf16(kf0, aq0, sc, 0, 0, 0);
        sc = __builtin_amdgcn_mfma_f32_16x16x32_bf16(kf1, aq1, sc, 0, 0, 0);
        // lane holds sc[j = j0 + qd*4 + r][i-local = c]
        ushort4 pk;
        pk.x = f2bf(sc[0]); pk.y = f2bf(sc[1]); pk.z = f2bf(sc[2]); pk.w = f2bf(sc[3]);
        *(ushort4*)(&sc_s[c * SCS + j0 + qd * 4]) = pk;
    }
    __syncthreads();

    // ---- phase B ----
    const float* sm = s_ws + bh * NN;
    float4 sv[4];
    #pragma unroll
    for (int seg = 0; seg < 4; ++seg)
        sv[seg] = *(const float4*)(sm + seg * 256 + lane * 4);

    const float* mbase = d_mask + (size_t)bh * NN * NN;
    const float* dbase = dirs + (size_t)b * NN * NN * 3;

    #pragma unroll
    for (int r4 = 0; r4 < 4; ++r4) {
        int il = w * 4 + r4;            // i-local 0..15
        int i = i0 + il;
        const float* mrow = mbase + (size_t)i * NN + lane * 4;
        const float* drow = dbase + ((size_t)i * NN + lane * 4) * 3;
        float l = 0.f, a0 = 0.f, a1 = 0.f, a2 = 0.f;
        #pragma unroll
        for (int seg = 0; seg < 4; ++seg) {
            float4 mk = *(const float4*)(mrow + seg * 256);
            float4 d0 = *(const float4*)(drow + seg * 768);
            float4 d1 = *(const float4*)(drow + seg * 768 + 4);
            float4 d2 = *(const float4*)(drow + seg * 768 + 8);
            ushort4 scv = *(const ushort4*)(&sc_s[il * SCS + seg * 256 + lane * 4]);
            float p0 = __expf(b2f(scv.x) + mk.x);
            float p1 = __expf(b2f(scv.y) + mk.y);
            float p2 = __expf(b2f(scv.z) + mk.z);
            float p3 = __expf(b2f(scv.w) + mk.w);
            l += p0 + p1 + p2 + p3;
            float t0 = p0 * sv[seg].x, t1 = p1 * sv[seg].y;
            float t2 = p2 * sv[seg].z, t3 = p3 * sv[seg].w;
            // dirs: j+0 -> d0.xyz ; j+1 -> d0.w d1.xy ; j+2 -> d1.zw d2.x ; j+3 -> d2.yzw
            a0 += t0 * d0.x + t1 * d0.w + t2 * d1.z + t3 * d2.y;
            a1 += t0 * d0.y + t1 * d1.x + t2 * d1.w + t3 * d2.z;
            a2 += t0 * d0.z + t1 * d1.y + t2 * d2.x + t3 * d2.w;
        }
        #pragma unroll
        for (int off = 1; off < 64; off <<= 1) {
            l  += __shfl_xor(l, off);
            a0 += __shfl_xor(a0, off);
            a1 += __shfl_xor(a1, off);
            a2 += __shfl_xor(a2, off);
        }
        if (lane == 0) {
            f32x4 o; o[0] = l; o[1] = a0; o[2] = a1; o[3] = a2;
            *(f32x4*)(part + ((size_t)bh * NN + i) * 4) = o;
        }
    }
}

// ---- k_fin: out[b,i,a] = b_force + sum_h acc[b,h,i,a] / l[b,h,i]
__global__ __launch_bounds__(256) void k_fin(const float4* __restrict__ part,
                                             const float* __restrict__ b_force,
                                             float* __restrict__ out) {
    int t = blockIdx.x * 256 + threadIdx.x;   // 0..4095
    int b = t >> 10, i = t & 1023;
    float o0, o1, o2;
    o0 = o1 = o2 = b_force[0];
    #pragma unroll
    for (int h = 0; h < NH; ++h) {
        float4 p = part[(((size_t)(b * NH + h)) << 10) + i];
        float inv = 1.0f / p.x;
        o0 += p.y * inv; o1 += p.z * inv; o2 += p.w * inv;
    }
    out[t * 3 + 0] = o0;
    out[t * 3 + 1] = o1;
    out[t * 3 + 2] = o2;
}

extern "C" void kernel_launch(void* const* d_in, const int* in_sizes, int n_in,
                              void* d_out, int out_size, void* d_ws, size_t ws_size,
                              hipStream_t stream) {
    (void)in_sizes; (void)n_in; (void)out_size; (void)ws_size;
    const float* emb     = (const float*)d_in[0];
    const float* dirs    = (const float*)d_in[1];
    const float* d_mask  = (const float*)d_in[2];
    const float* W       = (const float*)d_in[3];
    const float* b_proj  = (const float*)d_in[4];
    const float* w_force = (const float*)d_in[5];
    const float* b_force = (const float*)d_in[6];
    float* out = (float*)d_out;

    char* ws = (char*)d_ws;
    float* wv_eff   = (float*)ws;                       // 4096 f
    float* s_bias   = wv_eff + 4096;                    // 8 f
    float* bias_eff = s_bias + 8;                       // 1024 f
    float* s_ws     = bias_eff + 1024;                  // 32768 f
    unsigned short* Wt = (unsigned short*)(s_ws + 32768);    // 512K elems (1 MB)
    unsigned short* qb = Wt + 1024 * 512;               // 2M elems (4 MB)
    unsigned short* kb = qb + 4096 * 512;               // 2M elems (4 MB)
    float* part = (float*)(kb + 4096 * 512);            // 32*1024 float4 = 512 KB

    hipLaunchKernelGGL(k_prep, dim3(641),      dim3(256), 0, stream,
                       W, b_proj, w_force, Wt, bias_eff, wv_eff, s_bias);
    hipLaunchKernelGGL(k_s,    dim3(256),      dim3(128), 0, stream, emb, wv_eff, s_bias, s_ws);
    hipLaunchKernelGGL(k_gemm, dim3(32, 8),    dim3(256), 0, stream, emb, Wt, bias_eff, qb, kb);
    hipLaunchKernelGGL(k_attn, dim3(BB * NH * 64), dim3(256), 0, stream,
                       qb, kb, s_ws, d_mask, dirs, part);
    hipLaunchKernelGGL(k_fin,  dim3(16),       dim3(256), 0, stream, (const float4*)part, b_force, out);
}